// Round 1
// baseline (1457.755 us; speedup 1.0000x reference)
//
#include <hip/hip_runtime.h>
#include <stdint.h>

// ---------------- problem constants ----------------
#define S_LEN 2048
#define L_CH 16
#define T_CH (S_LEN * L_CH)   // 32768 chars
#define DC 128                // char emb/hidden
#define DW 512                // word emb
#define HWD 512               // word hidden
#define KW (DW + DC)          // 640
#define NTAG 64

// word-chunk scheme: 16 chunks x 128 payload, 48 warmup -> max 176 steps
#define WGROUPS 16
#define WMEMBERS 16
#define WSLOTS 184

// ---------------- ws layout (bytes) ----------------
// ctr:      u32 [16][184]                    @ 0          (11776 B)
// Hx:       f32 [16][184][512]               @ 11776      (6029312 B)
// xg_c:     bf16[32768][512]                 @ 6041088    (33554432 B)
// xg_w:     bf16[2048][2048]                 @ 39595520   (8388608 B)
// char_rep: f32 [2048][128]                  @ 47984128   (1048576 B)
// wh:       f32 [2048][512]                  @ 49032704   (4194304 B)
// total 53227008 B (~50.8 MB)
#define OFF_CTR  0
#define CTR_BYTES (WGROUPS * WSLOTS * 4)
#define OFF_HX   11776
#define OFF_XGC  6041088
#define OFF_XGW  39595520
#define OFF_CR   47984128
#define OFF_WH   49032704

// ---------------- helpers ----------------
__device__ __forceinline__ float b2f(unsigned short u) {
    return __uint_as_float(((unsigned int)u) << 16);
}
__device__ __forceinline__ unsigned short f2b(float f) {
    unsigned int u = __float_as_uint(f);
    unsigned int r = (u + 0x7fffu + ((u >> 16) & 1u)) >> 16;
    return (unsigned short)r;
}
__device__ __forceinline__ float sigm(float x) {
    float e = __builtin_amdgcn_exp2f(-1.442695041f * x);
    return __builtin_amdgcn_rcpf(1.f + e);
}
__device__ __forceinline__ float tanh_f(float x) {
    float e = __builtin_amdgcn_exp2f(2.885390082f * x);
    return 1.f - 2.f * __builtin_amdgcn_rcpf(e + 1.f);
}

// ---------------- xg GEMM: out[M][N](bf16) = gatherA[M][K] * Wih^T + bias ----
// MODE 0: A(r,k) = emb[idx[r]*128 + k]                       (char, K=128)
// MODE 1: A(r,k) = k<512 ? emb[idx[r]*512+k] : extra[r*128+k-512] (word, K=640)
template <int MODE>
__global__ __launch_bounds__(256) void xg_gemm(
    const int* __restrict__ idx, const float* __restrict__ emb,
    const float* __restrict__ extra, const float* __restrict__ Wih,
    const float* __restrict__ bias, unsigned short* __restrict__ out,
    int M, int N, int K)
{
    __shared__ __align__(16) float At[128][64];   // [k][m]
    __shared__ __align__(16) float Bt[128][128];  // [k][n]
    const int m0 = blockIdx.y * 64;
    const int n0 = blockIdx.x * 128;
    const int tid = threadIdx.x;
    const int tm = tid >> 4, tn = tid & 15;

    float acc[4][8];
#pragma unroll
    for (int i = 0; i < 4; i++)
#pragma unroll
        for (int j = 0; j < 8; j++) acc[i][j] = 0.f;

    const int a_row = tid >> 2;          // 0..63
    const int a_kq  = (tid & 3) * 4;     // 0,4,8,12
    const int b_row = tid >> 1;          // 0..127
    const int b_kq  = (tid & 1) * 4;     // 0,4

    for (int kk = 0; kk < K; kk += 128) {
        // ---- load A tile (gathered) ----
        {
            const float* src;
            int grow = m0 + a_row;
            if (MODE == 0) {
                src = emb + (long)idx[grow] * 128 + kk;
            } else {
                if (kk < 512) src = emb + (long)idx[grow] * 512 + kk;
                else          src = extra + (long)grow * 128 + (kk - 512);
            }
#pragma unroll
            for (int i = 0; i < 8; i++) {
                int k = a_kq + i * 16;
                float4 v = *(const float4*)(src + k);
                At[k + 0][a_row] = v.x; At[k + 1][a_row] = v.y;
                At[k + 2][a_row] = v.z; At[k + 3][a_row] = v.w;
            }
        }
        // ---- load B tile (Wih rows, transposed to [k][n]) ----
        {
            const float* src = Wih + (long)(n0 + b_row) * K + kk;
#pragma unroll
            for (int i = 0; i < 16; i++) {
                int k = b_kq + i * 8;
                float4 v = *(const float4*)(src + k);
                Bt[k + 0][b_row] = v.x; Bt[k + 1][b_row] = v.y;
                Bt[k + 2][b_row] = v.z; Bt[k + 3][b_row] = v.w;
            }
        }
        __syncthreads();
#pragma unroll 4
        for (int k = 0; k < 128; k++) {
            float4 av = *(const float4*)&At[k][tm * 4];
            float4 b0 = *(const float4*)&Bt[k][tn * 8];
            float4 b1 = *(const float4*)&Bt[k][tn * 8 + 4];
            float a_[4] = {av.x, av.y, av.z, av.w};
            float b_[8] = {b0.x, b0.y, b0.z, b0.w, b1.x, b1.y, b1.z, b1.w};
#pragma unroll
            for (int i = 0; i < 4; i++)
#pragma unroll
                for (int j = 0; j < 8; j++) acc[i][j] += a_[i] * b_[j];
        }
        __syncthreads();
    }
#pragma unroll
    for (int i = 0; i < 4; i++) {
        int mg = m0 + tm * 4 + i;
#pragma unroll
        for (int j = 0; j < 8; j++) {
            int ng = n0 + tn * 8 + j;
            out[(long)mg * N + ng] = f2b(acc[i][j] + bias[ng]);
        }
    }
}

// ---------------- char LSTM, chunked (256 chunks x (64 warm + 128 payload)) --
// 512 threads; thread t owns gate-row t of Whh_c (128 f32 in VGPRs).
__global__ __launch_bounds__(512, 2) void char_lstm(
    const float* __restrict__ Whh, const unsigned short* __restrict__ xg,
    float* __restrict__ char_rep)
{
    const int tid = threadIdx.x;
    const int chunk = blockIdx.x;
    float4 w4[32];
    {
        const float4* ws = (const float4*)(Whh + (long)tid * 128);
#pragma unroll
        for (int j = 0; j < 32; j++) w4[j] = ws[j];
    }
    __shared__ __align__(16) float h_lds[128];
    __shared__ float gates[512];
    if (tid < 128) h_lds[tid] = 0.f;
    float c_val = 0.f;
    int t_start = chunk * 128 - 64; if (t_start < 0) t_start = 0;
    const int t_end = chunk * 128 + 128;
    const int pay0 = chunk * 128;
    const int q = tid >> 7;
    __syncthreads();
    float xg_cur = b2f(xg[(long)t_start * 512 + tid]);
    for (int t = t_start; t < t_end; ++t) {
        float xg_nxt = 0.f;
        if (t + 1 < t_end) xg_nxt = b2f(xg[(long)(t + 1) * 512 + tid]);
        float a0 = 0.f, a1 = 0.f, a2 = 0.f, a3 = 0.f;
        const float4* h4 = (const float4*)h_lds;
#pragma unroll
        for (int j = 0; j < 32; j++) {
            float4 hv = h4[j];
            a0 += w4[j].x * hv.x; a1 += w4[j].y * hv.y;
            a2 += w4[j].z * hv.z; a3 += w4[j].w * hv.w;
        }
        float acc = xg_cur + ((a0 + a1) + (a2 + a3));
        gates[tid] = (q == 2) ? tanh_f(acc) : sigm(acc);
        __syncthreads();
        if (tid < 128) {
            float iv = gates[tid], fv = gates[128 + tid];
            float gv = gates[256 + tid], ov = gates[384 + tid];
            c_val = fv * c_val + iv * gv;
            float hv = ov * tanh_f(c_val);
            h_lds[tid] = hv;
            if (t >= pay0 && (t & 15) == 15)
                char_rep[(long)(t >> 4) * 128 + tid] = hv;
        }
        __syncthreads();
        xg_cur = xg_nxt;
    }
}

// ---------------- word LSTM, chunked, 16-CU groups ---------------------------
// 256 wgs x 1024 thr. group = bid&15 (chunk), member = bid>>4 (keeps a group's
// members on one XCD under the empirical %8 round-robin mapping).
// Member m owns h-units [m*32, m*32+32) -> 128 gate rows (64 f32 weights/thread).
// Per step: dot in regs -> 8-lane shfl reduce -> gates -> c/h update ->
// publish h-slice via agent-scope atomics -> counter barrier -> gather h[512].
__global__ __launch_bounds__(1024, 4) void word_lstm(
    const float* __restrict__ Whh, const unsigned short* __restrict__ xg,
    float* __restrict__ wh, float* __restrict__ Hx, unsigned int* __restrict__ ctr)
{
    const int bid = blockIdx.x;
    const int group = bid & 15;
    const int member = bid >> 4;
    const int tid = threadIdx.x;
    const int row_loc = tid >> 3;   // 0..127
    const int kseg = tid & 7;       // 0..7
    const int qg = row_loc >> 5;    // gate 0..3 (i,f,g,o)
    const int uloc = row_loc & 31;
    const int row_global = qg * 512 + member * 32 + uloc;

    float4 w4[16];
    {
        const float4* ws = (const float4*)(Whh + (long)row_global * 512 + kseg * 64);
#pragma unroll
        for (int j = 0; j < 16; j++) w4[j] = ws[j];
    }
    __shared__ __align__(16) float h_pad[8 * 68];  // 68-stride pad: conflict-free
    __shared__ float gates[128];
    if (tid < 544) h_pad[tid] = 0.f;
    float c_val = 0.f;
    int t_start = group * 128 - 48; if (t_start < 0) t_start = 0;
    const int t_end = group * 128 + 128;
    const int pay0 = group * 128;
    const int slot0 = -(group * 128 - 48);
    float* HxG = Hx + (long)group * WSLOTS * 512;
    unsigned int* ctrG = ctr + group * WSLOTS;
    __syncthreads();
    float xg_cur = 0.f;
    if (kseg == 0) xg_cur = b2f(xg[(long)t_start * 2048 + row_global]);
    for (int t = t_start; t < t_end; ++t) {
        const int slot = t + slot0;
        float xg_nxt = 0.f;
        if (kseg == 0 && t + 1 < t_end)
            xg_nxt = b2f(xg[(long)(t + 1) * 2048 + row_global]);
        float a0 = 0.f, a1 = 0.f, a2 = 0.f, a3 = 0.f;
        const float4* hseg = (const float4*)&h_pad[kseg * 68];
#pragma unroll
        for (int j = 0; j < 16; j++) {
            float4 hv = hseg[j];
            a0 += w4[j].x * hv.x; a1 += w4[j].y * hv.y;
            a2 += w4[j].z * hv.z; a3 += w4[j].w * hv.w;
        }
        float acc = (a0 + a1) + (a2 + a3);
        acc += __shfl_xor(acc, 1);
        acc += __shfl_xor(acc, 2);
        acc += __shfl_xor(acc, 4);
        if (kseg == 0) {
            float g = acc + xg_cur;
            gates[row_loc] = (qg == 2) ? tanh_f(g) : sigm(g);
        }
        __syncthreads();
        if (tid < 32) {
            float iv = gates[tid], fv = gates[32 + tid];
            float gv = gates[64 + tid], ov = gates[96 + tid];
            c_val = fv * c_val + iv * gv;
            float hv = ov * tanh_f(c_val);
            __hip_atomic_store(&HxG[(long)slot * 512 + member * 32 + tid], hv,
                               __ATOMIC_RELAXED, __HIP_MEMORY_SCOPE_AGENT);
            if (t >= pay0) wh[(long)t * 512 + member * 32 + tid] = hv;
        }
        __syncthreads();  // drains vmcnt: slice is at the coherent point
        if (tid == 0) {
            __hip_atomic_fetch_add(&ctrG[slot], 1u, __ATOMIC_RELEASE,
                                   __HIP_MEMORY_SCOPE_AGENT);
            int guard = 0;
            while (__hip_atomic_load(&ctrG[slot], __ATOMIC_ACQUIRE,
                                     __HIP_MEMORY_SCOPE_AGENT) < 16u) {
                __builtin_amdgcn_s_sleep(2);
                if (++guard > (1 << 22)) break;  // deadlock bailout -> absmax fail, not hang
            }
        }
        __syncthreads();
        if (tid < 512) {
            float hv = __hip_atomic_load(&HxG[(long)slot * 512 + tid],
                                         __ATOMIC_RELAXED, __HIP_MEMORY_SCOPE_AGENT);
            h_pad[(tid >> 6) * 68 + (tid & 63)] = hv;
        }
        __syncthreads();
        xg_cur = xg_nxt;
    }
}

// ---------------- tag projection + log_softmax -------------------------------
__global__ __launch_bounds__(64) void tag_out(
    const float* __restrict__ wh, const float* __restrict__ Wt,
    const float* __restrict__ bt, float* __restrict__ out)
{
    const int s = blockIdx.x;
    const int tt = threadIdx.x;  // 0..63
    const float4* h4 = (const float4*)(wh + (long)s * 512);
    const float4* w4 = (const float4*)(Wt + (long)tt * 512);
    float a0 = bt[tt], a1 = 0.f, a2 = 0.f, a3 = 0.f;
#pragma unroll 8
    for (int k = 0; k < 128; k++) {
        float4 a = h4[k], b = w4[k];
        a0 += a.x * b.x; a1 += a.y * b.y; a2 += a.z * b.z; a3 += a.w * b.w;
    }
    float acc = (a0 + a1) + (a2 + a3);
    float m = acc;
#pragma unroll
    for (int d = 1; d < 64; d <<= 1) m = fmaxf(m, __shfl_xor(m, d));
    float e = __builtin_amdgcn_exp2f((acc - m) * 1.442695041f);
    float ssum = e;
#pragma unroll
    for (int d = 1; d < 64; d <<= 1) ssum += __shfl_xor(ssum, d);
    float lse = __builtin_amdgcn_logf(ssum) * 0.6931471806f;
    out[(long)s * 64 + tt] = acc - m - lse;
}

// ---------------- launch -----------------------------------------------------
extern "C" void kernel_launch(void* const* d_in, const int* in_sizes, int n_in,
                              void* d_out, int out_size, void* d_ws, size_t ws_size,
                              hipStream_t stream)
{
    const int* sentence   = (const int*)d_in[0];
    const int* chars      = (const int*)d_in[1];
    const float* word_emb = (const float*)d_in[2];
    const float* char_emb = (const float*)d_in[3];
    const float* Wih_c    = (const float*)d_in[4];
    const float* Whh_c    = (const float*)d_in[5];
    const float* b_c      = (const float*)d_in[6];
    const float* Wih_w    = (const float*)d_in[7];
    const float* Whh_w    = (const float*)d_in[8];
    const float* b_w      = (const float*)d_in[9];
    const float* W_tag    = (const float*)d_in[10];
    const float* b_tag    = (const float*)d_in[11];
    float* out = (float*)d_out;

    char* ws = (char*)d_ws;
    unsigned int*   ctr      = (unsigned int*)(ws + OFF_CTR);
    float*          Hx       = (float*)(ws + OFF_HX);
    unsigned short* xg_c     = (unsigned short*)(ws + OFF_XGC);
    unsigned short* xg_w     = (unsigned short*)(ws + OFF_XGW);
    float*          char_rep = (float*)(ws + OFF_CR);
    float*          wh       = (float*)(ws + OFF_WH);

    hipMemsetAsync(ctr, 0, CTR_BYTES, stream);

    // 1) char-gate inputs: xg_c[32768][512] = char_emb[chars] @ Wih_c^T + b_c
    dim3 g1(512 / 128, T_CH / 64);
    xg_gemm<0><<<g1, 256, 0, stream>>>(chars, char_emb, nullptr, Wih_c, b_c,
                                       xg_c, T_CH, 4 * DC, DC);
    // 2) char LSTM chunks -> char_rep[2048][128]
    char_lstm<<<256, 512, 0, stream>>>(Whh_c, xg_c, char_rep);
    // 3) word-gate inputs: xg_w[2048][2048] = [we|char_rep] @ Wih_w^T + b_w
    dim3 g2(2048 / 128, S_LEN / 64);
    xg_gemm<1><<<g2, 256, 0, stream>>>(sentence, word_emb, char_rep, Wih_w, b_w,
                                       xg_w, S_LEN, 4 * HWD, KW);
    // 4) word LSTM chunks -> wh[2048][512]
    word_lstm<<<256, 1024, 0, stream>>>(Whh_w, xg_w, wh, Hx, ctr);
    // 5) tags + log_softmax -> out[2048][64]
    tag_out<<<S_LEN, 64, 0, stream>>>(wh, W_tag, b_tag, out);
}

// Round 3
// 1434.421 us; speedup vs baseline: 1.0163x; 1.0163x over previous
//
#include <hip/hip_runtime.h>
#include <stdint.h>

// ---------------- problem constants ----------------
#define S_LEN 2048
#define L_CH 16
#define T_CH (S_LEN * L_CH)   // 32768 chars
#define DC 128                // char emb/hidden
#define DW 512                // word emb
#define HWD 512               // word hidden
#define KW (DW + DC)          // 640
#define NTAG 64

// word-chunk scheme: 16 chunks x 128 payload, 48 warmup -> max 176 steps
#define WGROUPS 16
#define WMEMBERS 16
#define WSLOTS 184

// ---------------- ws layout (bytes) ----------------
// flags: u32 [16][184][16]   @ 0          (188416 B)
// Hx:    f32 [16][184][512]  @ 188416     (6029312 B)
// xg_c:  bf16[32768][512]    @ 6217728    (33554432 B)
// xg_w:  bf16[2048][2048]    @ 39772160   (8388608 B)
// char_rep: f32 [2048][128]  @ 48160768   (1048576 B)
// wh:    f32 [2048][512]     @ 49209344   (4194304 B)
// total 53403648 B (~50.9 MB)
#define OFF_FLG  0
#define FLG_BYTES (WGROUPS * WSLOTS * WMEMBERS * 4)
#define OFF_HX   188416
#define OFF_XGC  6217728
#define OFF_XGW  39772160
#define OFF_CR   48160768
#define OFF_WH   49209344

// ---------------- helpers ----------------
__device__ __forceinline__ float b2f(unsigned short u) {
    return __uint_as_float(((unsigned int)u) << 16);
}
__device__ __forceinline__ unsigned short f2b(float f) {
    unsigned int u = __float_as_uint(f);
    unsigned int r = (u + 0x7fffu + ((u >> 16) & 1u)) >> 16;
    return (unsigned short)r;
}
__device__ __forceinline__ float sigm(float x) {
    float e = __builtin_amdgcn_exp2f(-1.442695041f * x);
    return __builtin_amdgcn_rcpf(1.f + e);
}
__device__ __forceinline__ float tanh_f(float x) {
    float e = __builtin_amdgcn_exp2f(2.885390082f * x);
    return 1.f - 2.f * __builtin_amdgcn_rcpf(e + 1.f);
}
// Pin a float4 in VGPRs: value becomes an opaque asm result -> the compiler
// cannot rematerialize it from memory inside the loop (VGPR=52 bug, round 1).
#define PIN4(v) asm volatile("" : "+v"((v).x), "+v"((v).y), "+v"((v).z), "+v"((v).w))

// ---------------- xg GEMM: out[M][N](bf16) = gatherA[M][K] * Wih^T + bias ----
// MODE 0: A(r,k) = emb[idx[r]*128 + k]                       (char, K=128)
// MODE 1: A(r,k) = k<512 ? emb[idx[r]*512+k] : extra[r*128+k-512] (word, K=640)
template <int MODE>
__global__ __launch_bounds__(256) void xg_gemm(
    const int* __restrict__ idx, const float* __restrict__ emb,
    const float* __restrict__ extra, const float* __restrict__ Wih,
    const float* __restrict__ bias, unsigned short* __restrict__ out,
    int M, int N, int K)
{
    __shared__ __align__(16) float At[128][64];   // [k][m]
    __shared__ __align__(16) float Bt[128][128];  // [k][n]
    const int m0 = blockIdx.y * 64;
    const int n0 = blockIdx.x * 128;
    const int tid = threadIdx.x;
    const int tm = tid >> 4, tn = tid & 15;

    float acc[4][8];
#pragma unroll
    for (int i = 0; i < 4; i++)
#pragma unroll
        for (int j = 0; j < 8; j++) acc[i][j] = 0.f;

    const int a_row = tid >> 2;          // 0..63
    const int a_kq  = (tid & 3) * 4;     // 0,4,8,12
    const int b_row = tid >> 1;          // 0..127
    const int b_kq  = (tid & 1) * 4;     // 0,4

    for (int kk = 0; kk < K; kk += 128) {
        {
            const float* src;
            int grow = m0 + a_row;
            if (MODE == 0) {
                src = emb + (long)idx[grow] * 128 + kk;
            } else {
                if (kk < 512) src = emb + (long)idx[grow] * 512 + kk;
                else          src = extra + (long)grow * 128 + (kk - 512);
            }
#pragma unroll
            for (int i = 0; i < 8; i++) {
                int k = a_kq + i * 16;
                float4 v = *(const float4*)(src + k);
                At[k + 0][a_row] = v.x; At[k + 1][a_row] = v.y;
                At[k + 2][a_row] = v.z; At[k + 3][a_row] = v.w;
            }
        }
        {
            const float* src = Wih + (long)(n0 + b_row) * K + kk;
#pragma unroll
            for (int i = 0; i < 16; i++) {
                int k = b_kq + i * 8;
                float4 v = *(const float4*)(src + k);
                Bt[k + 0][b_row] = v.x; Bt[k + 1][b_row] = v.y;
                Bt[k + 2][b_row] = v.z; Bt[k + 3][b_row] = v.w;
            }
        }
        __syncthreads();
#pragma unroll 4
        for (int k = 0; k < 128; k++) {
            float4 av = *(const float4*)&At[k][tm * 4];
            float4 b0 = *(const float4*)&Bt[k][tn * 8];
            float4 b1 = *(const float4*)&Bt[k][tn * 8 + 4];
            float a_[4] = {av.x, av.y, av.z, av.w};
            float b_[8] = {b0.x, b0.y, b0.z, b0.w, b1.x, b1.y, b1.z, b1.w};
#pragma unroll
            for (int i = 0; i < 4; i++)
#pragma unroll
                for (int j = 0; j < 8; j++) acc[i][j] += a_[i] * b_[j];
        }
        __syncthreads();
    }
#pragma unroll
    for (int i = 0; i < 4; i++) {
        int mg = m0 + tm * 4 + i;
#pragma unroll
        for (int j = 0; j < 8; j++) {
            int ng = n0 + tn * 8 + j;
            out[(long)mg * N + ng] = f2b(acc[i][j] + bias[ng]);
        }
    }
}

// ---------------- char LSTM, chunked (256 chunks x (64 warm + 128 payload)) --
// 512 threads; thread t owns gate-row t of Whh_c (128 f32 in VGPRs, pinned).
// launch_bounds(512,1): 8 waves/wg -> 2 waves/SIMD -> 256-VGPR budget.
__global__ __launch_bounds__(512, 1) void char_lstm(
    const float* __restrict__ Whh, const unsigned short* __restrict__ xg,
    float* __restrict__ char_rep)
{
    const int tid = threadIdx.x;
    const int chunk = blockIdx.x;
    float4 w4[32];
    {
        const float4* ws = (const float4*)(Whh + (long)tid * 128);
#pragma unroll
        for (int j = 0; j < 32; j++) w4[j] = ws[j];
    }
#pragma unroll
    for (int j = 0; j < 32; j++) PIN4(w4[j]);

    __shared__ __align__(16) float h_lds[128];
    __shared__ float gates[512];
    if (tid < 128) h_lds[tid] = 0.f;
    float c_val = 0.f;
    int t_start = chunk * 128 - 64; if (t_start < 0) t_start = 0;
    const int t_end = chunk * 128 + 128;
    const int pay0 = chunk * 128;
    const int q = tid >> 7;
    __syncthreads();
    float xg_cur = b2f(xg[(long)t_start * 512 + tid]);
    for (int t = t_start; t < t_end; ++t) {
        float xg_nxt = 0.f;
        if (t + 1 < t_end) xg_nxt = b2f(xg[(long)(t + 1) * 512 + tid]);
        float a0 = 0.f, a1 = 0.f, a2 = 0.f, a3 = 0.f;
        const float4* h4 = (const float4*)h_lds;
#pragma unroll
        for (int j = 0; j < 32; j++) {
            float4 hv = h4[j];
            a0 += w4[j].x * hv.x; a1 += w4[j].y * hv.y;
            a2 += w4[j].z * hv.z; a3 += w4[j].w * hv.w;
        }
        float acc = xg_cur + ((a0 + a1) + (a2 + a3));
        gates[tid] = (q == 2) ? tanh_f(acc) : sigm(acc);
        __syncthreads();
        if (tid < 128) {
            float iv = gates[tid], fv = gates[128 + tid];
            float gv = gates[256 + tid], ov = gates[384 + tid];
            c_val = fv * c_val + iv * gv;
            float hv = ov * tanh_f(c_val);
            h_lds[tid] = hv;
            if (t >= pay0 && (t & 15) == 15)
                char_rep[(long)(t >> 4) * 128 + tid] = hv;
        }
        __syncthreads();
        xg_cur = xg_nxt;
    }
}

// ---------------- word LSTM, chunked, 16-CU groups ---------------------------
// 256 wgs x 1024 thr. group = bid&15, member = bid>>4 (group's members share
// an XCD under the empirical %8 round-robin mapping).
// Member m owns h-units [m*32,m*32+32) -> 128 gate rows (64 f32 weights/thread,
// pinned in VGPRs). Per step: reg dot -> 8-lane shfl reduce -> gates -> c/h ->
// publish slice -> per-member FLAG (release) -> 16-lane parallel poll -> gather.
__global__ __launch_bounds__(1024, 4) void word_lstm(
    const float* __restrict__ Whh, const unsigned short* __restrict__ xg,
    float* __restrict__ wh, float* __restrict__ Hx, unsigned int* __restrict__ flags)
{
    const int bid = blockIdx.x;
    const int group = bid & 15;
    const int member = bid >> 4;
    const int tid = threadIdx.x;
    const int row_loc = tid >> 3;   // 0..127
    const int kseg = tid & 7;       // 0..7
    const int qg = row_loc >> 5;    // gate 0..3 (i,f,g,o)
    const int uloc = row_loc & 31;
    const int row_global = qg * 512 + member * 32 + uloc;

    float4 w4[16];
    {
        const float4* ws = (const float4*)(Whh + (long)row_global * 512 + kseg * 64);
#pragma unroll
        for (int j = 0; j < 16; j++) w4[j] = ws[j];
    }
#pragma unroll
    for (int j = 0; j < 16; j++) PIN4(w4[j]);

    __shared__ __align__(16) float h_pad[8 * 68];  // 68-stride pad: conflict-free
    __shared__ float gates[128];
    if (tid < 544) h_pad[tid] = 0.f;
    float c_val = 0.f;
    int t_start = group * 128 - 48; if (t_start < 0) t_start = 0;
    const int t_end = group * 128 + 128;
    const int pay0 = group * 128;
    const int slot0 = -(group * 128 - 48);
    float* HxG = Hx + (long)group * WSLOTS * 512;
    unsigned int* flgG = flags + group * WSLOTS * WMEMBERS;
    __syncthreads();
    float xg_cur = 0.f;
    if (kseg == 0) xg_cur = b2f(xg[(long)t_start * 2048 + row_global]);
    for (int t = t_start; t < t_end; ++t) {
        const int slot = t + slot0;
        float xg_nxt = 0.f;
        if (kseg == 0 && t + 1 < t_end)
            xg_nxt = b2f(xg[(long)(t + 1) * 2048 + row_global]);
        float a0 = 0.f, a1 = 0.f, a2 = 0.f, a3 = 0.f;
        const float4* hseg = (const float4*)&h_pad[kseg * 68];
#pragma unroll
        for (int j = 0; j < 16; j++) {
            float4 hv = hseg[j];
            a0 += w4[j].x * hv.x; a1 += w4[j].y * hv.y;
            a2 += w4[j].z * hv.z; a3 += w4[j].w * hv.w;
        }
        float acc = (a0 + a1) + (a2 + a3);
        acc += __shfl_xor(acc, 1);
        acc += __shfl_xor(acc, 2);
        acc += __shfl_xor(acc, 4);
        if (kseg == 0) {
            float g = acc + xg_cur;
            gates[row_loc] = (qg == 2) ? tanh_f(g) : sigm(g);
        }
        __syncthreads();
        if (tid < 32) {
            float iv = gates[tid], fv = gates[32 + tid];
            float gv = gates[64 + tid], ov = gates[96 + tid];
            c_val = fv * c_val + iv * gv;
            float hv = ov * tanh_f(c_val);
            __hip_atomic_store(&HxG[(long)slot * 512 + member * 32 + tid], hv,
                               __ATOMIC_RELAXED, __HIP_MEMORY_SCOPE_AGENT);
            if (t >= pay0) wh[(long)t * 512 + member * 32 + tid] = hv;
        }
        __syncthreads();  // drains vmcnt: slice committed at L2 before flag
        if (tid == 0) {
            __hip_atomic_store(&flgG[slot * WMEMBERS + member], 1u,
                               __ATOMIC_RELEASE, __HIP_MEMORY_SCOPE_AGENT);
        }
        if (tid < 16) {
            // 16 lanes poll 16 contiguous flags (one 64B line) in parallel:
            // no RMW serialization (round-1 counter barrier cost ~3-4us/step).
            int guard = 0;
            while (__hip_atomic_load(&flgG[slot * WMEMBERS + tid], __ATOMIC_RELAXED,
                                     __HIP_MEMORY_SCOPE_AGENT) == 0u) {
                __builtin_amdgcn_s_sleep(1);
                if (++guard > (1 << 24)) break;  // bailout -> absmax fail, not hang
            }
            __builtin_amdgcn_fence(__ATOMIC_ACQUIRE, "agent");
        }
        __syncthreads();
        if (tid < 512) {
            float hv = __hip_atomic_load(&HxG[(long)slot * 512 + tid],
                                         __ATOMIC_RELAXED, __HIP_MEMORY_SCOPE_AGENT);
            h_pad[(tid >> 6) * 68 + (tid & 63)] = hv;
        }
        __syncthreads();
        xg_cur = xg_nxt;
    }
}

// ---------------- tag projection + log_softmax -------------------------------
__global__ __launch_bounds__(64) void tag_out(
    const float* __restrict__ wh, const float* __restrict__ Wt,
    const float* __restrict__ bt, float* __restrict__ out)
{
    const int s = blockIdx.x;
    const int tt = threadIdx.x;  // 0..63
    const float4* h4 = (const float4*)(wh + (long)s * 512);
    const float4* w4 = (const float4*)(Wt + (long)tt * 512);
    float a0 = bt[tt], a1 = 0.f, a2 = 0.f, a3 = 0.f;
#pragma unroll 8
    for (int k = 0; k < 128; k++) {
        float4 a = h4[k], b = w4[k];
        a0 += a.x * b.x; a1 += a.y * b.y; a2 += a.z * b.z; a3 += a.w * b.w;
    }
    float acc = (a0 + a1) + (a2 + a3);
    float m = acc;
#pragma unroll
    for (int d = 1; d < 64; d <<= 1) m = fmaxf(m, __shfl_xor(m, d));
    float e = __builtin_amdgcn_exp2f((acc - m) * 1.442695041f);
    float ssum = e;
#pragma unroll
    for (int d = 1; d < 64; d <<= 1) ssum += __shfl_xor(ssum, d);
    float lse = __builtin_amdgcn_logf(ssum) * 0.6931471806f;
    out[(long)s * 64 + tt] = acc - m - lse;
}

// ---------------- launch -----------------------------------------------------
extern "C" void kernel_launch(void* const* d_in, const int* in_sizes, int n_in,
                              void* d_out, int out_size, void* d_ws, size_t ws_size,
                              hipStream_t stream)
{
    const int* sentence   = (const int*)d_in[0];
    const int* chars      = (const int*)d_in[1];
    const float* word_emb = (const float*)d_in[2];
    const float* char_emb = (const float*)d_in[3];
    const float* Wih_c    = (const float*)d_in[4];
    const float* Whh_c    = (const float*)d_in[5];
    const float* b_c      = (const float*)d_in[6];
    const float* Wih_w    = (const float*)d_in[7];
    const float* Whh_w    = (const float*)d_in[8];
    const float* b_w      = (const float*)d_in[9];
    const float* W_tag    = (const float*)d_in[10];
    const float* b_tag    = (const float*)d_in[11];
    float* out = (float*)d_out;

    char* ws = (char*)d_ws;
    unsigned int*   flags    = (unsigned int*)(ws + OFF_FLG);
    float*          Hx       = (float*)(ws + OFF_HX);
    unsigned short* xg_c     = (unsigned short*)(ws + OFF_XGC);
    unsigned short* xg_w     = (unsigned short*)(ws + OFF_XGW);
    float*          char_rep = (float*)(ws + OFF_CR);
    float*          wh       = (float*)(ws + OFF_WH);

    (void)hipMemsetAsync(flags, 0, FLG_BYTES, stream);

    // 1) char-gate inputs: xg_c[32768][512] = char_emb[chars] @ Wih_c^T + b_c
    dim3 g1(512 / 128, T_CH / 64);
    xg_gemm<0><<<g1, 256, 0, stream>>>(chars, char_emb, nullptr, Wih_c, b_c,
                                       xg_c, T_CH, 4 * DC, DC);
    // 2) char LSTM chunks -> char_rep[2048][128]
    char_lstm<<<256, 512, 0, stream>>>(Whh_c, xg_c, char_rep);
    // 3) word-gate inputs: xg_w[2048][2048] = [we|char_rep] @ Wih_w^T + b_w
    dim3 g2(2048 / 128, S_LEN / 64);
    xg_gemm<1><<<g2, 256, 0, stream>>>(sentence, word_emb, char_rep, Wih_w, b_w,
                                       xg_w, S_LEN, 4 * HWD, KW);
    // 4) word LSTM chunks -> wh[2048][512]
    word_lstm<<<256, 1024, 0, stream>>>(Whh_w, xg_w, wh, Hx, flags);
    // 5) tags + log_softmax -> out[2048][64]
    tag_out<<<S_LEN, 64, 0, stream>>>(wh, W_tag, b_tag, out);
}